// Round 1
// baseline (333.838 us; speedup 1.0000x reference)
//
#include <hip/hip_runtime.h>

#define F_ 16384
#define D_ 768
#define C_ 16
#define BS_ 512
#define M_ (F_*C_)

// ---------------------------------------------------------------------------
// Transpose up_decoder [D, F] -> decT [F, D] so that column j becomes a
// contiguous 768-float row. Standard 32x32 LDS tile with +1 padding.
// ---------------------------------------------------------------------------
__global__ __launch_bounds__(256) void k_transpose(const float* __restrict__ in,
                                                   float* __restrict__ out) {
    __shared__ float tile[32][33];
    int tx = threadIdx.x & 31;
    int ty = threadIdx.x >> 5;          // 0..7
    int fcol = blockIdx.x * 32 + tx;    // F index
#pragma unroll
    for (int r = 0; r < 32; r += 8) {
        int drow = blockIdx.y * 32 + ty + r;   // D index
        tile[ty + r][tx] = in[(size_t)drow * F_ + fcol];
    }
    __syncthreads();
    int dcol = blockIdx.y * 32 + tx;    // D index
#pragma unroll
    for (int r = 0; r < 32; r += 8) {
        int frow = blockIdx.x * 32 + ty + r;   // F index
        out[(size_t)frow * D_ + dcol] = tile[tx][ty + r];
    }
}

// ---------------------------------------------------------------------------
// values[f*16+c] = dot(enc[f, :], decT[j[f*16+c], :]) over D=768.
// One block (4 waves) per feature f; each wave computes 4 connection dots.
// Per dot: 64 lanes x 3 float4 = 768 floats, coalesced; shuffle-reduce.
// ---------------------------------------------------------------------------
__global__ __launch_bounds__(256) void k_values(const float* __restrict__ enc,
                                                const float* __restrict__ decT,
                                                const int* __restrict__ jidx,
                                                float* __restrict__ values) {
    int f = blockIdx.x;
    int lane = threadIdx.x & 63;
    int wave = threadIdx.x >> 6;        // 0..3
    const float4* erow = (const float4*)(enc + (size_t)f * D_);
    float4 e0 = erow[lane];
    float4 e1 = erow[lane + 64];
    float4 e2 = erow[lane + 128];
#pragma unroll
    for (int t = 0; t < 4; ++t) {
        int c = (wave << 2) + t;
        int j = jidx[(f << 4) + c];
        const float4* drow = (const float4*)(decT + (size_t)j * D_);
        float4 d0 = drow[lane];
        float4 d1 = drow[lane + 64];
        float4 d2 = drow[lane + 128];
        float acc = e0.x * d0.x + e0.y * d0.y + e0.z * d0.z + e0.w * d0.w;
        acc      += e1.x * d1.x + e1.y * d1.y + e1.z * d1.z + e1.w * d1.w;
        acc      += e2.x * d2.x + e2.y * d2.y + e2.z * d2.z + e2.w * d2.w;
#pragma unroll
        for (int off = 32; off > 0; off >>= 1)
            acc += __shfl_down(acc, off, 64);
        if (lane == 0) values[(f << 4) + c] = acc;
    }
}

// ---------------------------------------------------------------------------
// Fallback (only if ws is too small for the transpose): read up_decoder
// columns directly (uncoalesced, L2/L3-absorbed). Correct but slower.
// ---------------------------------------------------------------------------
__global__ __launch_bounds__(256) void k_values_cols(const float* __restrict__ enc,
                                                     const float* __restrict__ dec,
                                                     const int* __restrict__ jidx,
                                                     float* __restrict__ values) {
    int f = blockIdx.x;
    int lane = threadIdx.x & 63;
    int wave = threadIdx.x >> 6;
    float e[12];
#pragma unroll
    for (int t = 0; t < 12; ++t)
        e[t] = enc[(size_t)f * D_ + lane + 64 * t];
#pragma unroll
    for (int tt = 0; tt < 4; ++tt) {
        int c = (wave << 2) + tt;
        int j = jidx[(f << 4) + c];
        float acc = 0.f;
#pragma unroll
        for (int t = 0; t < 12; ++t)
            acc += e[t] * dec[(size_t)(lane + 64 * t) * F_ + j];
#pragma unroll
        for (int off = 32; off > 0; off >>= 1)
            acc += __shfl_down(acc, off, 64);
        if (lane == 0) values[(f << 4) + c] = acc;
    }
}

// ---------------------------------------------------------------------------
// out[bs, f] = sum_c up[bs, j[f*16+c]] * values[f*16+c]
// One block (1024 threads) per bs row; stage the 64 KB up-row in LDS, then
// each thread computes 16 output features with 16 LDS gathers each.
// 64 KB LDS -> 2 blocks/CU -> 32 waves/CU.
// ---------------------------------------------------------------------------
__global__ __launch_bounds__(1024) void k_out(const float* __restrict__ up,
                                              const int* __restrict__ jidx,
                                              const float* __restrict__ values,
                                              float* __restrict__ out) {
    __shared__ float row[F_];           // 64 KB
    int bs = blockIdx.x;
    const float4* ur = (const float4*)(up + (size_t)bs * F_);
    float4* rr = (float4*)row;
#pragma unroll
    for (int t = 0; t < F_ / 4 / 1024; ++t)     // 4 iters
        rr[threadIdx.x + t * 1024] = ur[threadIdx.x + t * 1024];
    __syncthreads();
#pragma unroll
    for (int it = 0; it < F_ / 1024; ++it) {    // 16 iters
        int f = threadIdx.x + it * 1024;
        const int4*   jp = (const int4*)(jidx + ((size_t)f << 4));
        const float4* vp = (const float4*)(values + ((size_t)f << 4));
        float acc = 0.f;
#pragma unroll
        for (int q = 0; q < 4; ++q) {
            int4   j4 = jp[q];
            float4 v4 = vp[q];
            acc += row[j4.x] * v4.x + row[j4.y] * v4.y +
                   row[j4.z] * v4.z + row[j4.w] * v4.w;
        }
        out[(size_t)bs * F_ + f] = acc;
    }
}

extern "C" void kernel_launch(void* const* d_in, const int* in_sizes, int n_in,
                              void* d_out, int out_size, void* d_ws, size_t ws_size,
                              hipStream_t stream) {
    const float* up   = (const float*)d_in[0];  // up_facts   [B,S,F]
    const float* enc  = (const float*)d_in[1];  // down_encoder [F,D]
    const float* dec  = (const float*)d_in[2];  // up_decoder [D,F]
    // d_in[3] = i_indices, unused: i[m] = m >> 4 by construction
    const int*   jidx = (const int*)d_in[4];    // j_indices  [M]
    float*       out  = (float*)d_out;

    size_t decT_bytes = (size_t)F_ * D_ * sizeof(float);   // ~50.3 MB
    size_t val_bytes  = (size_t)M_ * sizeof(float);        // 1 MB

    if (ws_size >= decT_bytes + val_bytes) {
        float* decT   = (float*)d_ws;
        float* values = (float*)((char*)d_ws + decT_bytes);
        k_transpose<<<dim3(F_ / 32, D_ / 32), 256, 0, stream>>>(dec, decT);
        k_values<<<F_, 256, 0, stream>>>(enc, decT, jidx, values);
        k_out<<<BS_, 1024, 0, stream>>>(up, jidx, values, out);
    } else {
        float* values = (float*)d_ws;   // 1 MB
        k_values_cols<<<F_, 256, 0, stream>>>(enc, dec, jidx, values);
        k_out<<<BS_, 1024, 0, stream>>>(up, jidx, values, out);
    }
}

// Round 2
// 245.229 us; speedup vs baseline: 1.3613x; 1.3613x over previous
//
#include <hip/hip_runtime.h>
#include <hip/hip_bf16.h>

#define F_ 16384
#define D_ 768
#define C_ 16
#define BS_ 512
#define M_ (F_*C_)

static __device__ __forceinline__ float bf2f(unsigned short u) {
    return __uint_as_float(((unsigned int)u) << 16);
}

// ---------------------------------------------------------------------------
// Transpose + downconvert: up_decoder fp32 [D, F] -> decT bf16 [F, D].
// 32(F) x 64(D) tile; fp32 LDS tile, bf162-pair writes for coalescing.
// ---------------------------------------------------------------------------
__global__ __launch_bounds__(256) void k_transpose_bf16(const float* __restrict__ in,
                                                        unsigned short* __restrict__ out) {
    __shared__ float tile[64][33];      // [d_local][f_local], +1 pad
    int tx = threadIdx.x & 31;          // f_local
    int ty = threadIdx.x >> 5;          // 0..7
    int fcol = blockIdx.x * 32 + tx;
#pragma unroll
    for (int r = 0; r < 64; r += 8) {
        int drow = blockIdx.y * 64 + ty + r;
        tile[ty + r][tx] = in[(size_t)drow * F_ + fcol];
    }
    __syncthreads();
    int dp = threadIdx.x & 31;          // bf162 pair index within 64 dcols
    int fy = threadIdx.x >> 5;          // 0..7
#pragma unroll
    for (int r = 0; r < 32; r += 8) {
        int frow_l = fy + r;
        float v0 = tile[2 * dp][frow_l];
        float v1 = tile[2 * dp + 1][frow_l];
        unsigned int p = ((unsigned int)(__bfloat16_as_ushort(__float2bfloat16(v1))) << 16)
                       |  (unsigned int)(__bfloat16_as_ushort(__float2bfloat16(v0)));
        int frow = blockIdx.x * 32 + frow_l;
        unsigned int* o = (unsigned int*)(out + (size_t)frow * D_ + blockIdx.y * 64);
        o[dp] = p;
    }
}

// ---------------------------------------------------------------------------
// values[f*16+c] = dot(enc[f,:], decT[j[f*16+c],:]) over D=768, bf16 gather.
// One block per f, 4 waves x 4 connections. All 12 gathers issued before the
// reduction for memory-level parallelism.
// ---------------------------------------------------------------------------
__global__ __launch_bounds__(256) void k_values(const float* __restrict__ enc,
                                                const unsigned short* __restrict__ decT,
                                                const int* __restrict__ jidx,
                                                float* __restrict__ values) {
    int f = blockIdx.x;
    int lane = threadIdx.x & 63;
    int wave = threadIdx.x >> 6;        // 0..3
    const float4* erow = (const float4*)(enc + (size_t)f * D_);
    float4 e[3];
    e[0] = erow[lane];
    e[1] = erow[lane + 64];
    e[2] = erow[lane + 128];
    int4 j4 = *(const int4*)(jidx + (f << 4) + (wave << 2));
    int js[4] = {j4.x, j4.y, j4.z, j4.w};
    ushort4 g[4][3];
#pragma unroll
    for (int t = 0; t < 4; ++t) {
        const ushort4* drow = (const ushort4*)(decT + (size_t)js[t] * D_);
        g[t][0] = drow[lane];
        g[t][1] = drow[lane + 64];
        g[t][2] = drow[lane + 128];
    }
#pragma unroll
    for (int t = 0; t < 4; ++t) {
        float acc = 0.f;
#pragma unroll
        for (int k = 0; k < 3; ++k) {
            float4 ev = e[k];
            ushort4 dv = g[t][k];
            acc += ev.x * bf2f(dv.x) + ev.y * bf2f(dv.y)
                 + ev.z * bf2f(dv.z) + ev.w * bf2f(dv.w);
        }
#pragma unroll
        for (int off = 32; off > 0; off >>= 1)
            acc += __shfl_down(acc, off, 64);
        if (lane == 0) values[(f << 4) + (wave << 2) + t] = acc;
    }
}

// ---------------------------------------------------------------------------
// out[bs,f] = sum_c up[bs, j[f*16+c]] * values[f*16+c]
// One block per PAIR of bs rows. The two rows are staged interleaved as bf16
// pairs: LDS word f = (bf16 row0[f] | bf16 row1[f] << 16), so ONE ds_read_b32
// serves both rows. 64 KB LDS. Halves both LDS gather count and the per-block
// jidx/values L2 re-read traffic vs one-row blocks.
// ---------------------------------------------------------------------------
__global__ __launch_bounds__(1024) void k_out(const float* __restrict__ up,
                                              const int* __restrict__ jidx,
                                              const float* __restrict__ values,
                                              float* __restrict__ out) {
    __shared__ unsigned int rowp[F_];   // 64 KB: packed (row0, row1) bf16 pairs
    int bs0 = blockIdx.x << 1;
    const float4* u0 = (const float4*)(up + (size_t)bs0 * F_);
    const float4* u1 = (const float4*)(up + (size_t)(bs0 + 1) * F_);
#pragma unroll
    for (int t = 0; t < 4; ++t) {
        int idx = threadIdx.x + t * 1024;      // float4 index
        float4 a = u0[idx];
        float4 b = u1[idx];
        uint4 p;
        p.x = ((unsigned int)__bfloat16_as_ushort(__float2bfloat16(b.x)) << 16)
            |  (unsigned int)__bfloat16_as_ushort(__float2bfloat16(a.x));
        p.y = ((unsigned int)__bfloat16_as_ushort(__float2bfloat16(b.y)) << 16)
            |  (unsigned int)__bfloat16_as_ushort(__float2bfloat16(a.y));
        p.z = ((unsigned int)__bfloat16_as_ushort(__float2bfloat16(b.z)) << 16)
            |  (unsigned int)__bfloat16_as_ushort(__float2bfloat16(a.z));
        p.w = ((unsigned int)__bfloat16_as_ushort(__float2bfloat16(b.w)) << 16)
            |  (unsigned int)__bfloat16_as_ushort(__float2bfloat16(a.w));
        ((uint4*)rowp)[idx] = p;
    }
    __syncthreads();
#pragma unroll
    for (int it = 0; it < 16; ++it) {
        int f = threadIdx.x + it * 1024;
        const int4*   jp = (const int4*)(jidx + ((size_t)f << 4));
        const float4* vp = (const float4*)(values + ((size_t)f << 4));
        float a0 = 0.f, a1 = 0.f;
#pragma unroll
        for (int q = 0; q < 4; ++q) {
            int4   j4 = jp[q];
            float4 v4 = vp[q];
            unsigned int px = rowp[j4.x];
            unsigned int py = rowp[j4.y];
            unsigned int pz = rowp[j4.z];
            unsigned int pw = rowp[j4.w];
            a0 += bf2f((unsigned short)(px & 0xffff)) * v4.x
                + bf2f((unsigned short)(py & 0xffff)) * v4.y
                + bf2f((unsigned short)(pz & 0xffff)) * v4.z
                + bf2f((unsigned short)(pw & 0xffff)) * v4.w;
            a1 += bf2f((unsigned short)(px >> 16)) * v4.x
                + bf2f((unsigned short)(py >> 16)) * v4.y
                + bf2f((unsigned short)(pz >> 16)) * v4.z
                + bf2f((unsigned short)(pw >> 16)) * v4.w;
        }
        out[(size_t)bs0 * F_ + f] = a0;
        out[(size_t)(bs0 + 1) * F_ + f] = a1;
    }
}

extern "C" void kernel_launch(void* const* d_in, const int* in_sizes, int n_in,
                              void* d_out, int out_size, void* d_ws, size_t ws_size,
                              hipStream_t stream) {
    const float* up   = (const float*)d_in[0];  // up_facts   [B,S,F]
    const float* enc  = (const float*)d_in[1];  // down_encoder [F,D]
    const float* dec  = (const float*)d_in[2];  // up_decoder [D,F]
    // d_in[3] = i_indices, unused: i[m] = m >> 4 by construction
    const int*   jidx = (const int*)d_in[4];    // j_indices  [M]
    float*       out  = (float*)d_out;

    size_t decT_bytes = (size_t)F_ * D_ * sizeof(unsigned short);  // ~25.2 MB
    unsigned short* decT = (unsigned short*)d_ws;
    float* values = (float*)((char*)d_ws + decT_bytes);            // 1 MB

    k_transpose_bf16<<<dim3(F_ / 32, D_ / 64), 256, 0, stream>>>(dec, decT);
    k_values<<<F_, 256, 0, stream>>>(enc, decT, jidx, values);
    k_out<<<BS_ / 2, 1024, 0, stream>>>(up, jidx, values, out);
}

// Round 3
// 222.879 us; speedup vs baseline: 1.4978x; 1.1003x over previous
//
#include <hip/hip_runtime.h>
#include <hip/hip_bf16.h>

#define F_ 16384
#define D_ 768
#define C_ 16
#define BS_ 512
#define M_ (F_*C_)

static __device__ __forceinline__ float bf2f(unsigned short u) {
    return __uint_as_float(((unsigned int)u) << 16);
}
static __device__ __forceinline__ unsigned short f2bf(float f) {
    return __bfloat16_as_ushort(__float2bfloat16(f));
}

// ---------------------------------------------------------------------------
// Transpose + downconvert: up_decoder fp32 [D, F] -> decT bf16 [F, D].
// 64(D) x 64(F) tile; float4 global loads, uint2 (4 x bf16) packed stores.
// ---------------------------------------------------------------------------
__global__ __launch_bounds__(256) void k_transpose_bf16(const float* __restrict__ in,
                                                        unsigned short* __restrict__ out) {
    __shared__ float tile[64][65];      // [d_local][f_local], +1 pad
    int c4 = threadIdx.x & 15;          // float4 column (f)
    int r  = threadIdx.x >> 4;          // 0..15 (d)
    int fbase = blockIdx.x * 64;
    int dbase = blockIdx.y * 64;
#pragma unroll
    for (int k = 0; k < 4; ++k) {
        int drow = r + k * 16;
        float4 v = *(const float4*)(in + (size_t)(dbase + drow) * F_ + fbase + c4 * 4);
        tile[drow][c4 * 4 + 0] = v.x;
        tile[drow][c4 * 4 + 1] = v.y;
        tile[drow][c4 * 4 + 2] = v.z;
        tile[drow][c4 * 4 + 3] = v.w;
    }
    __syncthreads();
    int dp = threadIdx.x & 15;          // uint2 index (4 d-values each)
    int fr = threadIdx.x >> 4;          // 0..15 (f)
#pragma unroll
    for (int k = 0; k < 4; ++k) {
        int frow = fr + k * 16;
        float v0 = tile[4 * dp + 0][frow];
        float v1 = tile[4 * dp + 1][frow];
        float v2 = tile[4 * dp + 2][frow];
        float v3 = tile[4 * dp + 3][frow];
        uint2 p;
        p.x = ((unsigned int)f2bf(v1) << 16) | (unsigned int)f2bf(v0);
        p.y = ((unsigned int)f2bf(v3) << 16) | (unsigned int)f2bf(v2);
        *(uint2*)(out + (size_t)(fbase + frow) * D_ + dbase + dp * 4) = p;
    }
}

// ---------------------------------------------------------------------------
// Per-connection value: dot(enc[f,:], decT[j,:]) over D=768 (bf16 gather,
// fp32 accumulate). One block per f, 4 waves x 4 connections, all 12 gathers
// in flight before reduction. Emits the packed stream for k_out:
//   packed[m] = (bf16(value) << 16) | (u16)j        (j < 16384 fits u16)
// ---------------------------------------------------------------------------
__global__ __launch_bounds__(256) void k_values(const float* __restrict__ enc,
                                                const unsigned short* __restrict__ decT,
                                                const int* __restrict__ jidx,
                                                unsigned int* __restrict__ packed) {
    int f = blockIdx.x;
    int lane = threadIdx.x & 63;
    int wave = threadIdx.x >> 6;        // 0..3
    const float4* erow = (const float4*)(enc + (size_t)f * D_);
    float4 e[3];
    e[0] = erow[lane];
    e[1] = erow[lane + 64];
    e[2] = erow[lane + 128];
    int4 j4 = *(const int4*)(jidx + (f << 4) + (wave << 2));
    int js[4] = {j4.x, j4.y, j4.z, j4.w};
    ushort4 g[4][3];
#pragma unroll
    for (int t = 0; t < 4; ++t) {
        const ushort4* drow = (const ushort4*)(decT + (size_t)js[t] * D_);
        g[t][0] = drow[lane];
        g[t][1] = drow[lane + 64];
        g[t][2] = drow[lane + 128];
    }
#pragma unroll
    for (int t = 0; t < 4; ++t) {
        float acc = 0.f;
#pragma unroll
        for (int k = 0; k < 3; ++k) {
            float4 ev = e[k];
            ushort4 dv = g[t][k];
            acc += ev.x * bf2f(dv.x) + ev.y * bf2f(dv.y)
                 + ev.z * bf2f(dv.z) + ev.w * bf2f(dv.w);
        }
#pragma unroll
        for (int off = 32; off > 0; off >>= 1)
            acc += __shfl_down(acc, off, 64);
        if (lane == 0)
            packed[(f << 4) + (wave << 2) + t] =
                ((unsigned int)f2bf(acc) << 16) | (unsigned int)js[t];
    }
}

// ---------------------------------------------------------------------------
// out[bs,f] = sum_c up[bs, j]*v over the 16 connections of f.
// Block = (bs pair, f half): 512 blocks x 512 threads, 64 KB LDS
// -> 2 blocks/CU (16 waves/CU). The pair's rows are staged interleaved as
// bf16 in one 4 B LDS word, so one ds_read_b32 serves both rows. Connection
// stream is the packed (v<<16|j) uint: decode is mask/shift only.
// ---------------------------------------------------------------------------
__global__ __launch_bounds__(512) void k_out(const float* __restrict__ up,
                                             const unsigned int* __restrict__ packed,
                                             float* __restrict__ out) {
    __shared__ unsigned int rowp[F_];   // 64 KB
    int bs0  = (blockIdx.x >> 1) << 1;
    int half = blockIdx.x & 1;
    const float4* u0 = (const float4*)(up + (size_t)bs0 * F_);
    const float4* u1 = (const float4*)(up + (size_t)(bs0 + 1) * F_);
#pragma unroll
    for (int k = 0; k < 8; ++k) {
        int idx = threadIdx.x + k * 512;       // float4 index
        float4 a = u0[idx];
        float4 b = u1[idx];
        uint4 p;
        p.x = ((unsigned int)f2bf(b.x) << 16) | (unsigned int)f2bf(a.x);
        p.y = ((unsigned int)f2bf(b.y) << 16) | (unsigned int)f2bf(a.y);
        p.z = ((unsigned int)f2bf(b.z) << 16) | (unsigned int)f2bf(a.z);
        p.w = ((unsigned int)f2bf(b.w) << 16) | (unsigned int)f2bf(a.w);
        ((uint4*)rowp)[idx] = p;
    }
    __syncthreads();
    int f0 = half << 13;                       // 0 or 8192
#pragma unroll 4
    for (int it = 0; it < 16; ++it) {
        int f = f0 + threadIdx.x + it * 512;
        const uint4* sp = (const uint4*)(packed + ((size_t)f << 4));
        float a0 = 0.f, a1 = 0.f;
#pragma unroll
        for (int q = 0; q < 4; ++q) {
            uint4 w = sp[q];
#define CONN(ww) { unsigned int p_ = rowp[(ww) & 0xffffu];                  \
                   float v_ = __uint_as_float((ww) & 0xffff0000u);          \
                   a0 += __uint_as_float(p_ << 16) * v_;                    \
                   a1 += __uint_as_float(p_ & 0xffff0000u) * v_; }
            CONN(w.x) CONN(w.y) CONN(w.z) CONN(w.w)
#undef CONN
        }
        out[(size_t)bs0 * F_ + f] = a0;
        out[(size_t)(bs0 + 1) * F_ + f] = a1;
    }
}

extern "C" void kernel_launch(void* const* d_in, const int* in_sizes, int n_in,
                              void* d_out, int out_size, void* d_ws, size_t ws_size,
                              hipStream_t stream) {
    const float* up   = (const float*)d_in[0];  // up_facts   [B,S,F]
    const float* enc  = (const float*)d_in[1];  // down_encoder [F,D]
    const float* dec  = (const float*)d_in[2];  // up_decoder [D,F]
    // d_in[3] = i_indices, unused: i[m] = m >> 4 by construction
    const int*   jidx = (const int*)d_in[4];    // j_indices  [M]
    float*       out  = (float*)d_out;

    size_t decT_bytes = (size_t)F_ * D_ * sizeof(unsigned short);  // ~25.2 MB
    unsigned short* decT   = (unsigned short*)d_ws;
    unsigned int*   packed = (unsigned int*)((char*)d_ws + decT_bytes);  // 1 MB

    k_transpose_bf16<<<dim3(F_ / 64, D_ / 64), 256, 0, stream>>>(dec, decT);
    k_values<<<F_, 256, 0, stream>>>(enc, decT, jidx, packed);
    k_out<<<BS_, 512, 0, stream>>>(up, packed, out);
}